// Round 1
// baseline (7980.139 us; speedup 1.0000x reference)
//
#include <hip/hip_runtime.h>
#include <stdint.h>

#define USE_ASYNC 1

static const int T_ = 50;
static const int B_ = 512;
static const int BEL = 1024;
static const int S_ = 256;
static const int A_ = 32;
static const int EI_ = 1024;
static const int ES_ = 256;

typedef __attribute__((ext_vector_type(8))) short bf16x8;
typedef __attribute__((ext_vector_type(4))) float f32x4;

__device__ __forceinline__ short f2bf(float f) {
  union { float f; uint32_t u; } cv; cv.f = f;
  uint32_t u = cv.u;
  u = (u + 0x7fffu + ((u >> 16) & 1u)) >> 16;   // RNE
  return (short)u;
}

__device__ __forceinline__ float softplusf(float x) {
  return (x > 20.f) ? x : log1pf(expf(x));
}

// d_out layout (flat concat, fp32)
#define SZ_BEL_ALL (50ull * 512ull * 1024ull)
#define SZ_TBS     (50ull * 512ull * 256ull)
#define OFF_PS  (SZ_BEL_ALL)
#define OFF_PM  (OFF_PS + SZ_TBS)
#define OFF_PSD (OFF_PM + SZ_TBS)
#define OFF_QS  (OFF_PSD + SZ_TBS)
#define OFF_QM  (OFF_QS + SZ_TBS)
#define OFF_QSD (OFF_QM + SZ_TBS)

// ---------------- conversion fp32 -> bf16 (4/thread) ----------------
__global__ void k_convert(const float* __restrict__ src, short* __restrict__ dst, int n) {
  int i = (blockIdx.x * blockDim.x + threadIdx.x) * 4;
  if (i >= n) return;
  float4 v = *(const float4*)(src + i);
  short4 o;
  o.x = f2bf(v.x); o.y = f2bf(v.y); o.z = f2bf(v.z); o.w = f2bf(v.w);
  *(short4*)(dst + i) = o;
}

// ---------------- init: belief/post state ----------------
__global__ void k_init(const float* __restrict__ prev_belief, const float* __restrict__ prev_state,
                       float* __restrict__ belief_f32, short* __restrict__ belief_bf,
                       float* __restrict__ post_f32) {
  int i = blockIdx.x * blockDim.x + threadIdx.x;
  if (i < B_ * BEL) {
    float v = prev_belief[i];
    belief_f32[i] = v;
    belief_bf[i] = f2bf(v);
  } else {
    int k = i - B_ * BEL;
    if (k < B_ * S_) post_f32[k] = prev_state[k];
  }
}

// ---------------- per-step pack: xa = [post*nt, act], obs -> concat cols ----------------
__global__ void k_pack(const float* __restrict__ post, const float* __restrict__ nt,
                       const float* __restrict__ act, const float* __restrict__ oi,
                       const float* __restrict__ os,
                       short* __restrict__ xa, short* __restrict__ ei_in, short* __restrict__ es_in) {
  int i = blockIdx.x * blockDim.x + threadIdx.x;
  const int N1 = B_ * (S_ + A_);   // 147456
  const int N2 = B_ * EI_;         // 524288
  const int N3 = B_ * ES_;         // 131072
  if (i < N1) {
    int b = i / (S_ + A_), c = i % (S_ + A_);
    float v = (c < S_) ? post[b * S_ + c] * nt[b] : act[b * A_ + (c - S_)];
    xa[i] = f2bf(v);
  } else if (i < N1 + N2) {
    int k = i - N1;
    int b = k / EI_, c = k % EI_;
    ei_in[b * 2048 + 1024 + c] = f2bf(oi[k]);
  } else if (i < N1 + N2 + N3) {
    int k = i - N1 - N2;
    int b = k / ES_, c = k % ES_;
    es_in[b * 1280 + 1024 + c] = f2bf(os[k]);
  }
}

// ---------------- GRU elementwise ----------------
__global__ void k_gru(const float* __restrict__ gi, const float* __restrict__ gh,
                      const float* __restrict__ b_ih, const float* __restrict__ b_hh,
                      float* __restrict__ belief_f32, short* __restrict__ belief_bf,
                      short* __restrict__ ei_in, short* __restrict__ es_in,
                      float* __restrict__ out_beliefs_t) {
  int i = blockIdx.x * blockDim.x + threadIdx.x;
  if (i >= B_ * BEL) return;
  int b = i / BEL, j = i % BEL;
  size_t base = (size_t)b * 3 * BEL;
  float ir = gi[base + j]           + b_ih[j];
  float iz = gi[base + BEL + j]     + b_ih[BEL + j];
  float in_ = gi[base + 2 * BEL + j] + b_ih[2 * BEL + j];
  float hr = gh[base + j]           + b_hh[j];
  float hz = gh[base + BEL + j]     + b_hh[BEL + j];
  float hn = gh[base + 2 * BEL + j] + b_hh[2 * BEL + j];
  float rr = 1.f / (1.f + expf(-(ir + hr)));
  float zz = 1.f / (1.f + expf(-(iz + hz)));
  float nn = tanhf(in_ + rr * hn);
  float h = belief_f32[i];
  float hnew = (1.f - zz) * nn + zz * h;
  belief_f32[i] = hnew;
  out_beliefs_t[i] = hnew;
  short bv = f2bf(hnew);
  belief_bf[i] = bv;
  ei_in[b * 2048 + j] = bv;
  es_in[b * 1280 + j] = bv;
}

// ---------------- gauss heads split + PoE + output writes ----------------
__global__ void k_post(const float* __restrict__ ls_p, const float* __restrict__ ls_i,
                       const float* __restrict__ ls_s, float* __restrict__ post_f32,
                       float* __restrict__ out, int t) {
  int i = blockIdx.x * blockDim.x + threadIdx.x;
  if (i >= B_ * S_) return;
  int b = i / S_, j = i % S_;
  size_t r2 = (size_t)b * 2 * S_;
  float pl  = ls_p[r2 + j];
  float psc = softplusf(ls_p[r2 + S_ + j]) + 0.1f;
  float il  = ls_i[r2 + j];
  float isc = softplusf(ls_i[r2 + S_ + j]) + 0.1f;
  float sl  = ls_s[r2 + j];
  float ssc = softplusf(ls_s[r2 + S_ + j]) + 0.1f;
  float pi = 1.f / (isc * isc);
  float ps = 1.f / (ssc * ssc);
  float var = 1.f / (1.f + pi + ps);
  float ql = var * (il * pi + sl * ps);
  float qs = sqrtf(var);
  size_t tb = (size_t)t * B_ * S_ + i;
  out[OFF_PS + tb]  = pl;
  out[OFF_PM + tb]  = pl;
  out[OFF_PSD + tb] = psc;
  out[OFF_QS + tb]  = ql;
  out[OFF_QM + tb]  = ql;
  out[OFF_QSD + tb] = qs;
  post_f32[i] = ql;
}

// ---------------- generic bf16 MFMA GEMM: out = act(A[M,K] @ W[N,K]^T + bias) ----------------
struct Job {
  const short* A;     // [M,K] bf16
  const short* W;     // [N,K] bf16
  const float* bias;  // [N] fp32 or null
  float* outF;        // fp32 [M,N] or null
  short* outB;        // bf16 [M,N] or null
  int K;
  int relu;
};
struct Jobs { Job j[3]; };

#define BM 128
#define BN 128
#define BK 32

__global__ __launch_bounds__(256) void k_gemm(Jobs jobs, int N) {
  Job jb = jobs.j[blockIdx.z];
  const int tid = threadIdx.x;
  const int wave = tid >> 6;
  const int lane = tid & 63;
  const int quad = lane >> 4;
  const int r16 = lane & 15;
  const int mBase = blockIdx.y * BM;
  const int nBase = blockIdx.x * BN;
  const int K = jb.K;

  __shared__ short As[BM * BK];
  __shared__ short Bs[BN * BK];

  f32x4 acc[4][4];
#pragma unroll
  for (int a = 0; a < 4; ++a)
#pragma unroll
    for (int b = 0; b < 4; ++b)
      acc[a][b] = (f32x4){0.f, 0.f, 0.f, 0.f};

  const int srow = wave * 16 + (lane >> 2);   // 0..63
  const int scol = (lane & 3) * 8;            // 0,8,16,24
  const int waveM = (wave >> 1) * 64;
  const int waveN = (wave & 1) * 64;

  const short* Aptr = jb.A + (size_t)mBase * K;
  const short* Wptr = jb.W + (size_t)nBase * K;

  for (int k0 = 0; k0 < K; k0 += BK) {
    __syncthreads();
#pragma unroll
    for (int j = 0; j < 2; ++j) {
      const short* ga = Aptr + (size_t)(j * 64 + srow) * K + k0 + scol;
      const short* gb = Wptr + (size_t)(j * 64 + srow) * K + k0 + scol;
#if USE_ASYNC
      __builtin_amdgcn_global_load_lds(
          (const __attribute__((address_space(1))) void*)ga,
          (__attribute__((address_space(3))) void*)(&As[j * 2048 + wave * 512]), 16, 0, 0);
      __builtin_amdgcn_global_load_lds(
          (const __attribute__((address_space(1))) void*)gb,
          (__attribute__((address_space(3))) void*)(&Bs[j * 2048 + wave * 512]), 16, 0, 0);
#else
      *(uint4*)(&As[j * 2048 + tid * 8]) = *(const uint4*)ga;
      *(uint4*)(&Bs[j * 2048 + tid * 8]) = *(const uint4*)gb;
#endif
    }
    __syncthreads();

    bf16x8 af[4], bfr[4];
#pragma unroll
    for (int mi = 0; mi < 4; ++mi)
      af[mi] = *(const bf16x8*)(&As[(waveM + mi * 16 + r16) * BK + quad * 8]);
#pragma unroll
    for (int ni = 0; ni < 4; ++ni)
      bfr[ni] = *(const bf16x8*)(&Bs[(waveN + ni * 16 + r16) * BK + quad * 8]);
#pragma unroll
    for (int mi = 0; mi < 4; ++mi)
#pragma unroll
      for (int ni = 0; ni < 4; ++ni)
        acc[mi][ni] = __builtin_amdgcn_mfma_f32_16x16x32_bf16(af[mi], bfr[ni], acc[mi][ni], 0, 0, 0);
  }

#pragma unroll
  for (int mi = 0; mi < 4; ++mi) {
#pragma unroll
    for (int ni = 0; ni < 4; ++ni) {
#pragma unroll
      for (int reg = 0; reg < 4; ++reg) {
        int row = mBase + waveM + mi * 16 + quad * 4 + reg;
        int col = nBase + waveN + ni * 16 + r16;
        float v = acc[mi][ni][reg];
        if (jb.bias) v += jb.bias[col];
        if (jb.relu) v = v > 0.f ? v : 0.f;
        if (jb.outF) jb.outF[(size_t)row * N + col] = v;
        if (jb.outB) jb.outB[(size_t)row * N + col] = f2bf(v);
      }
    }
  }
}

extern "C" void kernel_launch(void* const* d_in, const int* in_sizes, int n_in,
                              void* d_out, int out_size, void* d_ws, size_t ws_size,
                              hipStream_t stream) {
  const float* prev_state  = (const float*)d_in[0];
  const float* actions     = (const float*)d_in[1];
  const float* prev_belief = (const float*)d_in[2];
  const float* obs_image   = (const float*)d_in[3];
  const float* obs_sound   = (const float*)d_in[4];
  const float* nonterm     = (const float*)d_in[5];
  const float* W_emb = (const float*)d_in[6];  const float* b_emb = (const float*)d_in[7];
  const float* W_ih  = (const float*)d_in[8];  const float* b_ih  = (const float*)d_in[9];
  const float* W_hh  = (const float*)d_in[10]; const float* b_hh  = (const float*)d_in[11];
  const float* W_s1  = (const float*)d_in[12]; const float* b_s1  = (const float*)d_in[13];
  const float* W_s2  = (const float*)d_in[14]; const float* b_s2  = (const float*)d_in[15];
  const float* W_ei1 = (const float*)d_in[16]; const float* b_ei1 = (const float*)d_in[17];
  const float* W_ei2 = (const float*)d_in[18]; const float* b_ei2 = (const float*)d_in[19];
  const float* W_es1 = (const float*)d_in[20]; const float* b_es1 = (const float*)d_in[21];
  const float* W_es2 = (const float*)d_in[22]; const float* b_es2 = (const float*)d_in[23];
  float* out = (float*)d_out;

  char* base = (char*)d_ws;
  size_t off = 0;
  auto alloc = [&](size_t bytes) -> void* {
    void* p = base + off;
    off += (bytes + 255) & ~(size_t)255;
    return p;
  };

  // bf16 weights
  short* Wemb_b = (short*)alloc((size_t)1024 * 288 * 2);
  short* Wih_b  = (short*)alloc((size_t)3072 * 1024 * 2);
  short* Whh_b  = (short*)alloc((size_t)3072 * 1024 * 2);
  short* Ws1_b  = (short*)alloc((size_t)1024 * 1024 * 2);
  short* Ws2_b  = (short*)alloc((size_t)512 * 1024 * 2);
  short* Wei1_b = (short*)alloc((size_t)1024 * 2048 * 2);
  short* Wei2_b = (short*)alloc((size_t)512 * 1024 * 2);
  short* Wes1_b = (short*)alloc((size_t)1024 * 1280 * 2);
  short* Wes2_b = (short*)alloc((size_t)512 * 1024 * 2);
  // state + per-step activations
  float* belief_f32 = (float*)alloc((size_t)B_ * BEL * 4);
  short* belief_bf  = (short*)alloc((size_t)B_ * BEL * 2);
  float* post_f32   = (float*)alloc((size_t)B_ * S_ * 4);
  short* xa_b       = (short*)alloc((size_t)B_ * 288 * 2);
  short* hidden_b   = (short*)alloc((size_t)B_ * 1024 * 2);
  float* gi_f       = (float*)alloc((size_t)B_ * 3072 * 4);
  float* gh_f       = (float*)alloc((size_t)B_ * 3072 * 4);
  short* ei_in      = (short*)alloc((size_t)B_ * 2048 * 2);
  short* es_in      = (short*)alloc((size_t)B_ * 1280 * 2);
  short* eih_b      = (short*)alloc((size_t)B_ * 1024 * 2);
  short* esh_b      = (short*)alloc((size_t)B_ * 1024 * 2);
  short* sh_b       = (short*)alloc((size_t)B_ * 1024 * 2);
  float* lsi_f      = (float*)alloc((size_t)B_ * 512 * 4);
  float* lss_f      = (float*)alloc((size_t)B_ * 512 * 4);
  float* lsp_f      = (float*)alloc((size_t)B_ * 512 * 4);

  // convert weights to bf16 (every call: ws is re-poisoned)
  struct Conv { const float* s; short* d; int n; };
  Conv convs[9] = {
      {W_emb, Wemb_b, 1024 * 288}, {W_ih, Wih_b, 3072 * 1024}, {W_hh, Whh_b, 3072 * 1024},
      {W_s1, Ws1_b, 1024 * 1024},  {W_s2, Ws2_b, 512 * 1024},  {W_ei1, Wei1_b, 1024 * 2048},
      {W_ei2, Wei2_b, 512 * 1024}, {W_es1, Wes1_b, 1024 * 1280}, {W_es2, Wes2_b, 512 * 1024}};
  for (int c = 0; c < 9; ++c) {
    int blocks = (convs[c].n / 4 + 255) / 256;
    k_convert<<<dim3(blocks), dim3(256), 0, stream>>>(convs[c].s, convs[c].d, convs[c].n);
  }

  k_init<<<dim3((B_ * BEL + B_ * S_) / 256), dim3(256), 0, stream>>>(
      prev_belief, prev_state, belief_f32, belief_bf, post_f32);

  for (int t = 0; t < T_; ++t) {
    k_pack<<<dim3(3136), dim3(256), 0, stream>>>(
        post_f32, nonterm + (size_t)t * B_, actions + (size_t)t * B_ * A_,
        obs_image + (size_t)t * B_ * EI_, obs_sound + (size_t)t * B_ * ES_,
        xa_b, ei_in, es_in);

    {  // emb: hidden = relu(xa @ W_emb^T + b_emb)   [512,288] -> [512,1024] bf16
      Jobs jb{};
      jb.j[0] = Job{xa_b, Wemb_b, b_emb, nullptr, hidden_b, 288, 1};
      jb.j[1] = jb.j[0]; jb.j[2] = jb.j[0];
      k_gemm<<<dim3(8, 4, 1), dim3(256), 0, stream>>>(jb, 1024);
    }
    {  // gates: gi = hidden @ W_ih^T ; gh = belief @ W_hh^T  -> [512,3072] fp32 each
      Jobs jb{};
      jb.j[0] = Job{hidden_b, Wih_b, nullptr, gi_f, nullptr, 1024, 0};
      jb.j[1] = Job{belief_bf, Whh_b, nullptr, gh_f, nullptr, 1024, 0};
      jb.j[2] = jb.j[0];
      k_gemm<<<dim3(24, 4, 2), dim3(256), 0, stream>>>(jb, 3072);
    }
    k_gru<<<dim3(2048), dim3(256), 0, stream>>>(gi_f, gh_f, b_ih, b_hh, belief_f32, belief_bf,
                                                ei_in, es_in, out + (size_t)t * B_ * BEL);
    {  // head layer 1: ei1 (K=2048), es1 (K=1280), s1 (K=1024)  -> [512,1024] bf16, relu
      Jobs jb{};
      jb.j[0] = Job{ei_in, Wei1_b, b_ei1, nullptr, eih_b, 2048, 1};
      jb.j[1] = Job{es_in, Wes1_b, b_es1, nullptr, esh_b, 1280, 1};
      jb.j[2] = Job{belief_bf, Ws1_b, b_s1, nullptr, sh_b, 1024, 1};
      k_gemm<<<dim3(8, 4, 3), dim3(256), 0, stream>>>(jb, 1024);
    }
    {  // head layer 2: -> [512,512] fp32 (loc|scale_pre)
      Jobs jb{};
      jb.j[0] = Job{eih_b, Wei2_b, b_ei2, lsi_f, nullptr, 1024, 0};
      jb.j[1] = Job{esh_b, Wes2_b, b_es2, lss_f, nullptr, 1024, 0};
      jb.j[2] = Job{sh_b, Ws2_b, b_s2, lsp_f, nullptr, 1024, 0};
      k_gemm<<<dim3(4, 4, 3), dim3(256), 0, stream>>>(jb, 512);
    }
    k_post<<<dim3(512), dim3(256), 0, stream>>>(lsp_f, lsi_f, lss_f, post_f32, out, t);
  }
}

// Round 2
// 5322.268 us; speedup vs baseline: 1.4994x; 1.4994x over previous
//
#include <hip/hip_runtime.h>
#include <stdint.h>

static const int T_ = 50;
static const int B_ = 512;
static const int BEL = 1024;
static const int S_ = 256;
static const int A_ = 32;
static const int EI_ = 1024;
static const int ES_ = 256;

typedef __attribute__((ext_vector_type(8))) short bf16x8;
typedef __attribute__((ext_vector_type(4))) float f32x4;

__device__ __forceinline__ short f2bf(float f) {
  union { float f; uint32_t u; } cv; cv.f = f;
  uint32_t u = cv.u;
  u = (u + 0x7fffu + ((u >> 16) & 1u)) >> 16;   // RNE
  return (short)u;
}
__device__ __forceinline__ float bf2f(short s) {
  union { uint32_t u; float f; } cv;
  cv.u = ((uint32_t)(uint16_t)s) << 16;
  return cv.f;
}
__device__ __forceinline__ float softplusf(float x) {
  return (x > 20.f) ? x : log1pf(expf(x));
}

// d_out layout (flat concat, fp32)
#define SZ_BEL_ALL (50ull * 512ull * 1024ull)
#define SZ_TBS     (50ull * 512ull * 256ull)
#define OFF_PS  (SZ_BEL_ALL)
#define OFF_PM  (OFF_PS + SZ_TBS)
#define OFF_PSD (OFF_PM + SZ_TBS)
#define OFF_QS  (OFF_PSD + SZ_TBS)
#define OFF_QM  (OFF_QS + SZ_TBS)
#define OFF_QSD (OFF_QM + SZ_TBS)

// ---------------- conversion fp32 -> bf16 (4/thread) ----------------
__global__ void k_convert(const float* __restrict__ src, short* __restrict__ dst, int n) {
  int i = (blockIdx.x * blockDim.x + threadIdx.x) * 4;
  if (i >= n) return;
  float4 v = *(const float4*)(src + i);
  short4 o;
  o.x = f2bf(v.x); o.y = f2bf(v.y); o.z = f2bf(v.z); o.w = f2bf(v.w);
  *(short4*)(dst + i) = o;
}

// ---------------- init: belief + st0 = prev_state * nt0 ----------------
__global__ void k_init(const float* __restrict__ prev_belief, const float* __restrict__ prev_state,
                       const float* __restrict__ nt0,
                       float* __restrict__ belief_f32, short* __restrict__ belief_bf,
                       short* __restrict__ st_bf) {
  int i = blockIdx.x * blockDim.x + threadIdx.x;
  if (i < B_ * BEL) {
    float v = prev_belief[i];
    belief_f32[i] = v;
    belief_bf[i] = f2bf(v);
  } else {
    int k = i - B_ * BEL;
    if (k < B_ * S_) {
      int b = k / S_;
      st_bf[k] = f2bf(prev_state[k] * nt0[b]);
    }
  }
}

// ---------------- GRU elementwise ----------------
__global__ void k_gru(const float* __restrict__ gi, const float* __restrict__ gh,
                      const float* __restrict__ b_ih, const float* __restrict__ b_hh,
                      float* __restrict__ belief_f32, short* __restrict__ belief_bf,
                      float* __restrict__ out_beliefs_t) {
  int i = blockIdx.x * blockDim.x + threadIdx.x;
  if (i >= B_ * BEL) return;
  int b = i / BEL, j = i % BEL;
  size_t base = (size_t)b * 3 * BEL;
  float ir = gi[base + j]            + b_ih[j];
  float iz = gi[base + BEL + j]      + b_ih[BEL + j];
  float in_ = gi[base + 2 * BEL + j] + b_ih[2 * BEL + j];
  float hr = gh[base + j]            + b_hh[j];
  float hz = gh[base + BEL + j]      + b_hh[BEL + j];
  float hn = gh[base + 2 * BEL + j]  + b_hh[2 * BEL + j];
  float rr = 1.f / (1.f + expf(-(ir + hr)));
  float zz = 1.f / (1.f + expf(-(iz + hz)));
  float nn = tanhf(in_ + rr * hn);
  float h = belief_f32[i];
  float hnew = (1.f - zz) * nn + zz * h;
  belief_f32[i] = hnew;
  out_beliefs_t[i] = hnew;
  belief_bf[i] = f2bf(hnew);
}

// ---------------- gauss heads split + PoE + output writes + next st ----------------
__global__ void k_post(const float* __restrict__ ls_p, const float* __restrict__ ls_i,
                       const float* __restrict__ ls_s, const float* __restrict__ nt_next,
                       short* __restrict__ st_bf, float* __restrict__ out, int t) {
  int i = blockIdx.x * blockDim.x + threadIdx.x;
  if (i >= B_ * S_) return;
  int b = i / S_, j = i % S_;
  size_t r2 = (size_t)b * 2 * S_;
  float pl  = ls_p[r2 + j];
  float psc = softplusf(ls_p[r2 + S_ + j]) + 0.1f;
  float il  = ls_i[r2 + j];
  float isc = softplusf(ls_i[r2 + S_ + j]) + 0.1f;
  float sl  = ls_s[r2 + j];
  float ssc = softplusf(ls_s[r2 + S_ + j]) + 0.1f;
  float pi = 1.f / (isc * isc);
  float ps = 1.f / (ssc * ssc);
  float var = 1.f / (1.f + pi + ps);
  float ql = var * (il * pi + sl * ps);
  float qs = sqrtf(var);
  size_t tb = (size_t)t * B_ * S_ + i;
  out[OFF_PS + tb]  = pl;
  out[OFF_PM + tb]  = pl;
  out[OFF_PSD + tb] = psc;
  out[OFF_QS + tb]  = ql;
  out[OFF_QM + tb]  = ql;
  out[OFF_QSD + tb] = qs;
  if (nt_next) st_bf[i] = f2bf(ql * nt_next[b]);
}

// ---------------- generic bf16 MFMA GEMM ----------------
// out = act(A[M,K(lda)] @ W[N,K(ldw)]^T + bias + Cadd)
struct Job {
  const short* A;      // [M,*] bf16, row stride lda
  int lda;
  const short* W;      // [N,*] bf16, row stride ldw
  int ldw;
  const float* bias;   // [N] fp32 or null
  const short* Cadd;   // bf16 [M,N] per-element add, or null
  float* outF;         // fp32 [M,N] or null
  short* outB;         // bf16 [M,N] or null
  int K;
  int relu;
};
struct Jobs { Job j[3]; };

template <int BM, int BN>
__global__ __launch_bounds__(256) void k_gemm(Jobs jobs, int N) {
  Job jb = jobs.j[blockIdx.z];
  const int tid = threadIdx.x;
  const int wave = tid >> 6;
  const int lane = tid & 63;
  const int quad = lane >> 4;
  const int r16 = lane & 15;
  const int mBase = blockIdx.y * BM;
  const int nBase = blockIdx.x * BN;
  const int K = jb.K;
  const int lda = jb.lda;
  const int ldw = jb.ldw;

  __shared__ short As[BM * 32];
  __shared__ short Bs[BN * 32];

  constexpr int WM = BM / 2, WN = BN / 2;
  constexpr int TM = WM / 16, TN = WN / 16;
  const int waveM = (wave >> 1) * WM;
  const int waveN = (wave & 1) * WN;

  f32x4 acc[TM][TN];
#pragma unroll
  for (int a = 0; a < TM; ++a)
#pragma unroll
    for (int b = 0; b < TN; ++b)
      acc[a][b] = (f32x4){0.f, 0.f, 0.f, 0.f};

  const short* Aptr = jb.A + (size_t)mBase * lda;
  const short* Wptr = jb.W + (size_t)nBase * ldw;
  const int srow = tid >> 2;          // 0..63 within a 64-row chunk
  const int scol = (tid & 3) * 8;     // 0,8,16,24

  for (int k0 = 0; k0 < K; k0 += 32) {
    __syncthreads();
#pragma unroll
    for (int c = 0; c < BM / 64; ++c) {
      const short* g = Aptr + (size_t)(c * 64 + srow) * lda + k0 + scol;
      __builtin_amdgcn_global_load_lds(
          (const __attribute__((address_space(1))) void*)g,
          (__attribute__((address_space(3))) void*)(&As[c * 2048 + wave * 512]), 16, 0, 0);
    }
#pragma unroll
    for (int c = 0; c < BN / 64; ++c) {
      const short* g = Wptr + (size_t)(c * 64 + srow) * ldw + k0 + scol;
      __builtin_amdgcn_global_load_lds(
          (const __attribute__((address_space(1))) void*)g,
          (__attribute__((address_space(3))) void*)(&Bs[c * 2048 + wave * 512]), 16, 0, 0);
    }
    __syncthreads();

    bf16x8 af[TM], bfr[TN];
#pragma unroll
    for (int mi = 0; mi < TM; ++mi)
      af[mi] = *(const bf16x8*)(&As[(waveM + mi * 16 + r16) * 32 + quad * 8]);
#pragma unroll
    for (int ni = 0; ni < TN; ++ni)
      bfr[ni] = *(const bf16x8*)(&Bs[(waveN + ni * 16 + r16) * 32 + quad * 8]);
#pragma unroll
    for (int mi = 0; mi < TM; ++mi)
#pragma unroll
      for (int ni = 0; ni < TN; ++ni)
        acc[mi][ni] = __builtin_amdgcn_mfma_f32_16x16x32_bf16(af[mi], bfr[ni], acc[mi][ni], 0, 0, 0);
  }

#pragma unroll
  for (int mi = 0; mi < TM; ++mi) {
#pragma unroll
    for (int ni = 0; ni < TN; ++ni) {
#pragma unroll
      for (int reg = 0; reg < 4; ++reg) {
        int row = mBase + waveM + mi * 16 + quad * 4 + reg;
        int col = nBase + waveN + ni * 16 + r16;
        float v = acc[mi][ni][reg];
        if (jb.bias) v += jb.bias[col];
        if (jb.Cadd) v += bf2f(jb.Cadd[(size_t)row * N + col]);
        if (jb.relu) v = v > 0.f ? v : 0.f;
        if (jb.outF) jb.outF[(size_t)row * N + col] = v;
        if (jb.outB) jb.outB[(size_t)row * N + col] = f2bf(v);
      }
    }
  }
}

extern "C" void kernel_launch(void* const* d_in, const int* in_sizes, int n_in,
                              void* d_out, int out_size, void* d_ws, size_t ws_size,
                              hipStream_t stream) {
  const float* prev_state  = (const float*)d_in[0];
  const float* actions     = (const float*)d_in[1];
  const float* prev_belief = (const float*)d_in[2];
  const float* obs_image   = (const float*)d_in[3];
  const float* obs_sound   = (const float*)d_in[4];
  const float* nonterm     = (const float*)d_in[5];
  const float* W_emb = (const float*)d_in[6];  const float* b_emb = (const float*)d_in[7];
  const float* W_ih  = (const float*)d_in[8];  const float* b_ih  = (const float*)d_in[9];
  const float* W_hh  = (const float*)d_in[10]; const float* b_hh  = (const float*)d_in[11];
  const float* W_s1  = (const float*)d_in[12]; const float* b_s1  = (const float*)d_in[13];
  const float* W_s2  = (const float*)d_in[14]; const float* b_s2  = (const float*)d_in[15];
  const float* W_ei1 = (const float*)d_in[16]; const float* b_ei1 = (const float*)d_in[17];
  const float* W_ei2 = (const float*)d_in[18]; const float* b_ei2 = (const float*)d_in[19];
  const float* W_es1 = (const float*)d_in[20]; const float* b_es1 = (const float*)d_in[21];
  const float* W_es2 = (const float*)d_in[22]; const float* b_es2 = (const float*)d_in[23];
  float* out = (float*)d_out;

  char* base = (char*)d_ws;
  size_t off = 0;
  auto alloc = [&](size_t bytes) -> void* {
    void* p = base + off;
    off += (bytes + 255) & ~(size_t)255;
    return p;
  };

  const size_t TB = (size_t)T_ * B_;  // 25600

  // bf16 weights (full matrices; splits via lda/ptr offset)
  short* Wemb_b = (short*)alloc((size_t)1024 * 288 * 2);
  short* Wih_b  = (short*)alloc((size_t)3072 * 1024 * 2);
  short* Whh_b  = (short*)alloc((size_t)3072 * 1024 * 2);
  short* Ws1_b  = (short*)alloc((size_t)1024 * 1024 * 2);
  short* Ws2_b  = (short*)alloc((size_t)512 * 1024 * 2);
  short* Wei1_b = (short*)alloc((size_t)1024 * 2048 * 2);
  short* Wei2_b = (short*)alloc((size_t)512 * 1024 * 2);
  short* Wes1_b = (short*)alloc((size_t)1024 * 1280 * 2);
  short* Wes2_b = (short*)alloc((size_t)512 * 1024 * 2);
  // bf16 inputs for batched precompute
  short* oi_bf  = (short*)alloc(TB * EI_ * 2);
  short* os_bf  = (short*)alloc(TB * ES_ * 2);
  short* act_bf = (short*)alloc(TB * A_ * 2);
  // precomputed contributions (bf16)
  short* OI_c   = (short*)alloc(TB * 1024 * 2);
  short* OS_c   = (short*)alloc(TB * 1024 * 2);
  short* ACT_c  = (short*)alloc(TB * 1024 * 2);
  // state + per-step activations
  float* belief_f32 = (float*)alloc((size_t)B_ * BEL * 4);
  short* belief_bf  = (short*)alloc((size_t)B_ * BEL * 2);
  short* st_bf      = (short*)alloc((size_t)B_ * S_ * 2);
  short* hidden_b   = (short*)alloc((size_t)B_ * 1024 * 2);
  float* gi_f       = (float*)alloc((size_t)B_ * 3072 * 4);
  float* gh_f       = (float*)alloc((size_t)B_ * 3072 * 4);
  short* eih_b      = (short*)alloc((size_t)B_ * 1024 * 2);
  short* esh_b      = (short*)alloc((size_t)B_ * 1024 * 2);
  short* sh_b       = (short*)alloc((size_t)B_ * 1024 * 2);
  float* lsi_f      = (float*)alloc((size_t)B_ * 512 * 4);
  float* lss_f      = (float*)alloc((size_t)B_ * 512 * 4);
  float* lsp_f      = (float*)alloc((size_t)B_ * 512 * 4);

  // fp32 -> bf16 conversions (ws re-poisoned each call, so every call)
  struct Conv { const float* s; short* d; size_t n; };
  Conv convs[12] = {
      {W_emb, Wemb_b, 1024 * 288}, {W_ih, Wih_b, 3072 * 1024}, {W_hh, Whh_b, 3072 * 1024},
      {W_s1, Ws1_b, 1024 * 1024},  {W_s2, Ws2_b, 512 * 1024},  {W_ei1, Wei1_b, 1024 * 2048},
      {W_ei2, Wei2_b, 512 * 1024}, {W_es1, Wes1_b, 1024 * 1280}, {W_es2, Wes2_b, 512 * 1024},
      {obs_image, oi_bf, TB * EI_}, {obs_sound, os_bf, TB * ES_}, {actions, act_bf, TB * A_}};
  for (int c = 0; c < 12; ++c) {
    int blocks = (int)((convs[c].n / 4 + 255) / 256);
    k_convert<<<dim3(blocks), dim3(256), 0, stream>>>(convs[c].s, convs[c].d, (int)convs[c].n);
  }

  // batched contributions: OI = oi @ W_ei1[:,1024:]^T + b_ei1 ; OS ; ACT (+b folded)
  {
    Jobs jb{};
    jb.j[0] = Job{oi_bf, 1024, Wei1_b + 1024, 2048, b_ei1, nullptr, nullptr, OI_c, 1024, 0};
    jb.j[1] = jb.j[0]; jb.j[2] = jb.j[0];
    k_gemm<128, 128><<<dim3(8, 200, 1), dim3(256), 0, stream>>>(jb, 1024);
  }
  {
    Jobs jb{};
    jb.j[0] = Job{os_bf, 256, Wes1_b + 1024, 1280, b_es1, nullptr, nullptr, OS_c, 256, 0};
    jb.j[1] = jb.j[0]; jb.j[2] = jb.j[0];
    k_gemm<128, 128><<<dim3(8, 200, 1), dim3(256), 0, stream>>>(jb, 1024);
  }
  {
    Jobs jb{};
    jb.j[0] = Job{act_bf, 32, Wemb_b + 256, 288, b_emb, nullptr, nullptr, ACT_c, 32, 0};
    jb.j[1] = jb.j[0]; jb.j[2] = jb.j[0];
    k_gemm<128, 128><<<dim3(8, 200, 1), dim3(256), 0, stream>>>(jb, 1024);
  }

  k_init<<<dim3((B_ * BEL + B_ * S_) / 256), dim3(256), 0, stream>>>(
      prev_belief, prev_state, nonterm, belief_f32, belief_bf, st_bf);

  for (int t = 0; t < T_; ++t) {
    {  // emb: hidden = relu(st @ W_emb[:,:256]^T + ACT_c[t])  [512,256]->[512,1024] bf16
      Jobs jb{};
      jb.j[0] = Job{st_bf, 256, Wemb_b, 288, nullptr, ACT_c + (size_t)t * B_ * 1024,
                    nullptr, hidden_b, 256, 1};
      jb.j[1] = jb.j[0]; jb.j[2] = jb.j[0];
      k_gemm<64, 64><<<dim3(16, 8, 1), dim3(256), 0, stream>>>(jb, 1024);
    }
    {  // gates: gi = hidden @ W_ih^T ; gh = belief @ W_hh^T  -> [512,3072] fp32
      Jobs jb{};
      jb.j[0] = Job{hidden_b, 1024, Wih_b, 1024, nullptr, nullptr, gi_f, nullptr, 1024, 0};
      jb.j[1] = Job{belief_bf, 1024, Whh_b, 1024, nullptr, nullptr, gh_f, nullptr, 1024, 0};
      jb.j[2] = jb.j[0];
      k_gemm<128, 64><<<dim3(48, 4, 2), dim3(256), 0, stream>>>(jb, 3072);
    }
    k_gru<<<dim3(2048), dim3(256), 0, stream>>>(gi_f, gh_f, b_ih, b_hh,
                                                belief_f32, belief_bf,
                                                out + (size_t)t * B_ * BEL);
    {  // head layer 1 (all K=1024): eih, esh (obs part precomputed), sh
      Jobs jb{};
      jb.j[0] = Job{belief_bf, 1024, Wei1_b, 2048, nullptr, OI_c + (size_t)t * B_ * 1024,
                    nullptr, eih_b, 1024, 1};
      jb.j[1] = Job{belief_bf, 1024, Wes1_b, 1280, nullptr, OS_c + (size_t)t * B_ * 1024,
                    nullptr, esh_b, 1024, 1};
      jb.j[2] = Job{belief_bf, 1024, Ws1_b, 1024, b_s1, nullptr, nullptr, sh_b, 1024, 1};
      k_gemm<128, 64><<<dim3(16, 4, 3), dim3(256), 0, stream>>>(jb, 1024);
    }
    {  // head layer 2: -> [512,512] fp32 (loc|scale_pre)
      Jobs jb{};
      jb.j[0] = Job{eih_b, 1024, Wei2_b, 1024, b_ei2, nullptr, lsi_f, nullptr, 1024, 0};
      jb.j[1] = Job{esh_b, 1024, Wes2_b, 1024, b_es2, nullptr, lss_f, nullptr, 1024, 0};
      jb.j[2] = Job{sh_b, 1024, Ws2_b, 1024, b_s2, nullptr, lsp_f, nullptr, 1024, 0};
      k_gemm<64, 64><<<dim3(8, 8, 3), dim3(256), 0, stream>>>(jb, 512);
    }
    const float* ntn = (t + 1 < T_) ? (nonterm + (size_t)(t + 1) * B_) : nullptr;
    k_post<<<dim3(512), dim3(256), 0, stream>>>(lsp_f, lsi_f, lss_f, ntn, st_bf, out, t);
  }
}